// Round 6
// baseline (513.144 us; speedup 1.0000x reference)
//
#include <hip/hip_runtime.h>

// VQ argmin: x [16,64,64,64] NCHW fp32, codebook [1024,64] fp32.
// N = 65536 rows, D = 64, K = 1024. dist = ||e||^2 - 2 x.e (||x||^2 dropped).
//
// R6 = R5 with the token-pasting bug fixed ((C##0).x instead of C##0.x).
// Structure: x tile in LDS (aligned b128, bank-balanced), codebook streamed by
// inline-asm global_load_dwordx4 from an SGPR base + immediate offsets (zero
// per-load VALU), double-buffered via s_waitcnt vmcnt(8). fmacs: v_fmac v,v,v.

typedef float f4 __attribute__((ext_vector_type(4)));

#define K_CODES 1024
#define D_DIM   64
#define HW      4096   // 64*64
#define ROWS    64     // rows per block

__global__ __launch_bounds__(256) void enorm_kernel(const float* __restrict__ cb,
                                                    float* __restrict__ enorm) {
    int k = blockIdx.x * 256 + threadIdx.x;   // grid 4x256 -> 1024
    const f4* row = (const f4*)(cb + (size_t)k * D_DIM);
    float s = 0.f;
#pragma unroll
    for (int i = 0; i < D_DIM / 4; ++i) {
        f4 v = row[i];
        s = fmaf(v.x, v.x, s);
        s = fmaf(v.y, v.y, s);
        s = fmaf(v.z, v.z, s);
        s = fmaf(v.w, v.w, s);
    }
    enorm[k] = s;
}

// Issue 8 prefetch loads (next chunk, codes 0..7 at row stride 256B) from SGPR
// base NB, then wait until the CURRENT chunk's 8 loads (issued one call ago)
// have landed. A* = current buffer (tied so consumers order after the wait);
// B* = prefetch destination (stays in flight until the next call's wait).
#define CHUNK_ASM(A0,A1,A2,A3,A4,A5,A6,A7, B0,B1,B2,B3,B4,B5,B6,B7, NB)      \
    asm volatile(                                                            \
        "global_load_dwordx4 %8,  %16, %17 offset:0\n\t"                     \
        "global_load_dwordx4 %9,  %16, %17 offset:256\n\t"                   \
        "global_load_dwordx4 %10, %16, %17 offset:512\n\t"                   \
        "global_load_dwordx4 %11, %16, %17 offset:768\n\t"                   \
        "global_load_dwordx4 %12, %16, %17 offset:1024\n\t"                  \
        "global_load_dwordx4 %13, %16, %17 offset:1280\n\t"                  \
        "global_load_dwordx4 %14, %16, %17 offset:1536\n\t"                  \
        "global_load_dwordx4 %15, %16, %17 offset:1792\n\t"                  \
        "s_waitcnt vmcnt(8)"                                                 \
        : "+v"(A0), "+v"(A1), "+v"(A2), "+v"(A3),                            \
          "+v"(A4), "+v"(A5), "+v"(A6), "+v"(A7),                            \
          "=v"(B0), "=v"(B1), "=v"(B2), "=v"(B3),                            \
          "=v"(B4), "=v"(B5), "=v"(B6), "=v"(B7)                             \
        : "v"(vz), "s"((const void*)(NB)));

#define FMAS(C, X)                                                               \
    acc0 = fmaf((C##0).x, X.x, acc0); acc0 = fmaf((C##0).y, X.y, acc0);          \
    acc0 = fmaf((C##0).z, X.z, acc0); acc0 = fmaf((C##0).w, X.w, acc0);          \
    acc1 = fmaf((C##1).x, X.x, acc1); acc1 = fmaf((C##1).y, X.y, acc1);          \
    acc1 = fmaf((C##1).z, X.z, acc1); acc1 = fmaf((C##1).w, X.w, acc1);          \
    acc2 = fmaf((C##2).x, X.x, acc2); acc2 = fmaf((C##2).y, X.y, acc2);          \
    acc2 = fmaf((C##2).z, X.z, acc2); acc2 = fmaf((C##2).w, X.w, acc2);          \
    acc3 = fmaf((C##3).x, X.x, acc3); acc3 = fmaf((C##3).y, X.y, acc3);          \
    acc3 = fmaf((C##3).z, X.z, acc3); acc3 = fmaf((C##3).w, X.w, acc3);          \
    acc4 = fmaf((C##4).x, X.x, acc4); acc4 = fmaf((C##4).y, X.y, acc4);          \
    acc4 = fmaf((C##4).z, X.z, acc4); acc4 = fmaf((C##4).w, X.w, acc4);          \
    acc5 = fmaf((C##5).x, X.x, acc5); acc5 = fmaf((C##5).y, X.y, acc5);          \
    acc5 = fmaf((C##5).z, X.z, acc5); acc5 = fmaf((C##5).w, X.w, acc5);          \
    acc6 = fmaf((C##6).x, X.x, acc6); acc6 = fmaf((C##6).y, X.y, acc6);          \
    acc6 = fmaf((C##6).z, X.z, acc6); acc6 = fmaf((C##6).w, X.w, acc6);          \
    acc7 = fmaf((C##7).x, X.x, acc7); acc7 = fmaf((C##7).y, X.y, acc7);          \
    acc7 = fmaf((C##7).z, X.z, acc7); acc7 = fmaf((C##7).w, X.w, acc7);

#define DO_CHUNK_E(dc, NB) { const f4 x4 = xrow4[dc];                        \
    CHUNK_ASM(E0,E1,E2,E3,E4,E5,E6,E7, F0,F1,F2,F3,F4,F5,F6,F7, NB)         \
    FMAS(E, x4) }
#define DO_CHUNK_F(dc, NB) { const f4 x4 = xrow4[dc];                        \
    CHUNK_ASM(F0,F1,F2,F3,F4,F5,F6,F7, E0,E1,E2,E3,E4,E5,E6,E7, NB)         \
    FMAS(F, x4) }

__global__ __launch_bounds__(256, 4) void vq_kernel(const float* __restrict__ x,
                                                    const float* __restrict__ cb,
                                                    const float* __restrict__ enorm,
                                                    int* __restrict__ out) {
    __shared__ f4    xs4[ROWS][17];   // row stride 272B: 16B-aligned, bank-balanced
    __shared__ float sEn[K_CODES];
    __shared__ float sd[256];
    __shared__ int   si[256];

    const int tid = threadIdx.x;
    const int r = tid & 63;
    const int quarter = __builtin_amdgcn_readfirstlane(tid >> 6);
    const int n0 = blockIdx.x * ROWS;
    const int b = n0 >> 12;
    const int hw0 = n0 & (HW - 1);

    // stage e-norms (prep kernel output) into LDS
#pragma unroll
    for (int q = 0; q < 4; ++q) sEn[q * 256 + tid] = enorm[q * 256 + tid];

    // stage x tile: wave q loads channels q*16..q*16+15 of all 64 rows
    {
        const float* g = x + ((size_t)b * D_DIM + quarter * 16) * HW + hw0 + r;
        float v[16];
#pragma unroll
        for (int i = 0; i < 16; ++i) v[i] = g[(size_t)i * HW];
#pragma unroll
        for (int j = 0; j < 4; ++j)
            xs4[r][quarter * 4 + j] = (f4){v[4*j], v[4*j+1], v[4*j+2], v[4*j+3]};
    }
    __syncthreads();

    const f4* xrow4 = &xs4[r][0];
    float best = __builtin_inff();
    int bestk = 0;

    int vz = 0;                        // zero voffset VGPR for the asm loads
    f4 E0,E1,E2,E3,E4,E5,E6,E7;        // double buffers (asm-owned)
    f4 F0,F1,F2,F3,F4,F5,F6,F7;

    const char* tp = (const char*)(cb + (size_t)quarter * 256 * D_DIM);
    const char* const cb0 = (const char*)cb;

    // prologue: launch chunk (t=0, dc=0) into E
    asm volatile(
        "global_load_dwordx4 %0, %8, %9 offset:0\n\t"
        "global_load_dwordx4 %1, %8, %9 offset:256\n\t"
        "global_load_dwordx4 %2, %8, %9 offset:512\n\t"
        "global_load_dwordx4 %3, %8, %9 offset:768\n\t"
        "global_load_dwordx4 %4, %8, %9 offset:1024\n\t"
        "global_load_dwordx4 %5, %8, %9 offset:1280\n\t"
        "global_load_dwordx4 %6, %8, %9 offset:1536\n\t"
        "global_load_dwordx4 %7, %8, %9 offset:1792"
        : "=v"(E0), "=v"(E1), "=v"(E2), "=v"(E3),
          "=v"(E4), "=v"(E5), "=v"(E6), "=v"(E7)
        : "v"(vz), "s"((const void*)tp));

#pragma unroll 1
    for (int t = 0; t < 32; ++t) {
        float acc0=0.f, acc1=0.f, acc2=0.f, acc3=0.f;
        float acc4=0.f, acc5=0.f, acc6=0.f, acc7=0.f;
        // last prefetch of the last tile would run off cb: refetch cb[0] instead
        const char* nb_last = (t < 31) ? (tp + 2048) : cb0;

        DO_CHUNK_E(0,  tp + 16)   DO_CHUNK_F(1,  tp + 32)
        DO_CHUNK_E(2,  tp + 48)   DO_CHUNK_F(3,  tp + 64)
        DO_CHUNK_E(4,  tp + 80)   DO_CHUNK_F(5,  tp + 96)
        DO_CHUNK_E(6,  tp + 112)  DO_CHUNK_F(7,  tp + 128)
        DO_CHUNK_E(8,  tp + 144)  DO_CHUNK_F(9,  tp + 160)
        DO_CHUNK_E(10, tp + 176)  DO_CHUNK_F(11, tp + 192)
        DO_CHUNK_E(12, tp + 208)  DO_CHUNK_F(13, tp + 224)
        DO_CHUNK_E(14, tp + 240)  DO_CHUNK_F(15, nb_last)

        const int kq = (quarter << 8) + (t << 3);
#define FIN(c) { const float dd = fmaf(-2.f, acc##c, sEn[kq + (c)]);         \
                 if (dd < best) { best = dd; bestk = kq + (c); } }
        FIN(0) FIN(1) FIN(2) FIN(3) FIN(4) FIN(5) FIN(6) FIN(7)
#undef FIN
        tp += 2048;
    }

    // drain the trailing (discarded) prefetch before regalloc may reuse E0..E7
    asm volatile("s_waitcnt vmcnt(0)"
                 : "+v"(E0), "+v"(E1), "+v"(E2), "+v"(E3),
                   "+v"(E4), "+v"(E5), "+v"(E6), "+v"(E7));

    // combine 4 K-quarters per row; lower quarter (lower k) wins ties
    sd[tid] = best;
    si[tid] = bestk;
    __syncthreads();
    if (quarter == 0) {
#pragma unroll
        for (int q = 1; q < 4; ++q) {
            const float o = sd[q * 64 + r];
            const int  oi = si[q * 64 + r];
            if (o < best) { best = o; bestk = oi; }
        }
        out[n0 + r] = bestk;
    }
}

extern "C" void kernel_launch(void* const* d_in, const int* in_sizes, int n_in,
                              void* d_out, int out_size, void* d_ws, size_t ws_size,
                              hipStream_t stream) {
    const float* x  = (const float*)d_in[0];   // [16,64,64,64] fp32
    const float* cb = (const float*)d_in[1];   // [1024,64] fp32
    float* enorm = (float*)d_ws;               // 1024 floats scratch
    int*   out   = (int*)d_out;                // 65536 int32 indices

    enorm_kernel<<<dim3(K_CODES / 256), dim3(256), 0, stream>>>(cb, enorm);
    vq_kernel<<<dim3(65536 / ROWS), dim3(256), 0, stream>>>(x, cb, enorm, out);
}